// Round 1
// 475.050 us; speedup vs baseline: 1.0239x; 1.0239x over previous
//
#include <hip/hip_runtime.h>
#include <hip/hip_bf16.h>
#include <cstdint>
#include <cstddef>

#define S_LEN 2048
#define NHEADS 32
#define NKVH   8
#define HDIM   128

using bf16x8 = __attribute__((ext_vector_type(8))) short;
using f32x4  = __attribute__((ext_vector_type(4))) float;
using f32x16 = __attribute__((ext_vector_type(16))) float;

__device__ __forceinline__ short f2bf(float f) {
  union { float f; unsigned u; } a; a.f = f;
  unsigned u = a.u;
  unsigned r = u + 0x7fffu + ((u >> 16) & 1u);   // RNE
  return (short)(r >> 16);
}
__device__ __forceinline__ unsigned pack_bf2(float lo, float hi) {
  union { float f; unsigned u; } a, b; a.f = lo; b.f = hi;
  return __builtin_amdgcn_perm(b.u, a.u, 0x07060302);
}

// async 16B global -> LDS (wave-uniform base + lane*16 on HW)
__device__ __forceinline__ void gld16(const void* g, void* l) {
  __builtin_amdgcn_global_load_lds((__attribute__((address_space(1))) void*)(void*)g,
                                   (__attribute__((address_space(3))) void*)l, 16, 0, 0);
}

#define VMWAIT(N) asm volatile("s_waitcnt vmcnt(" #N ")" ::: "memory")
#define SCHEDB()  __builtin_amdgcn_sched_barrier(0)
#define MFMA16(a, b, c) __builtin_amdgcn_mfma_f32_16x16x32_bf16((a), (b), (c), 0, 0, 0)

// ---------------- fp32 -> bf16 elementwise (x4 vectorized) ----------------
__global__ void cvt_f32_bf16(const float* __restrict__ x, short* __restrict__ y, int n4) {
  int i = blockIdx.x * blockDim.x + threadIdx.x;
  if (i >= n4) return;
  float4 v = reinterpret_cast<const float4*>(x)[i];
  short4 o;
  o.x = f2bf(v.x); o.y = f2bf(v.y); o.z = f2bf(v.z); o.w = f2bf(v.w);
  reinterpret_cast<short4*>(y)[i] = o;
}

// ------------- transpose + convert: W[K][N] fp32 -> Wt[N][K] bf16 -------------
__global__ __launch_bounds__(256)
void transpose_to_bf16(const float* __restrict__ W, short* __restrict__ Wt,
                       int K, int N) {
  __shared__ float tile[32 * 33];
  const int bn = blockIdx.x * 32, bk = blockIdx.y * 32;
  const int t = threadIdx.x;
  const int c4 = t & 7, kr = t >> 3;
  float4 v = *(const float4*)&W[(size_t)(bk + kr) * N + bn + c4 * 4];
  tile[kr * 33 + c4 * 4 + 0] = v.x;
  tile[kr * 33 + c4 * 4 + 1] = v.y;
  tile[kr * 33 + c4 * 4 + 2] = v.z;
  tile[kr * 33 + c4 * 4 + 3] = v.w;
  __syncthreads();
  const int k4 = t & 7, nr = t >> 3;
  short4 o;
  o.x = f2bf(tile[(k4 * 4 + 0) * 33 + nr]);
  o.y = f2bf(tile[(k4 * 4 + 1) * 33 + nr]);
  o.z = f2bf(tile[(k4 * 4 + 2) * 33 + nr]);
  o.w = f2bf(tile[(k4 * 4 + 3) * 33 + nr]);
  *(short4*)&Wt[(size_t)(bn + nr) * K + bk + k4 * 4] = o;
}

// ---------------- fused QKV GEMM + RoPE epilogue ----------------
// 256x256 tile, BK=64, 8 waves (2Mx4N), per-wave 128x64 output.
// LDS 128KB: A/B double-buffered, each K-tile split into two 16KB K-half
// regions (256 rows x 32 shorts, 64B rows -> bank-uniform ds_read_b128,
// and global_load_lds linear dest maps row-major exactly).
// 4 phases per K-tile; raw s_barrier + counted vmcnt(8) at phases 1 and 3
// keep staged loads ~1.5 K-tiles in flight across barriers.
//
// LDS map (shorts): A(p,kh) = p*16384 + kh*8192 ; B(p,kh) = 32768 + p*16384 + kh*8192
//
// Region-retirement schedule (tile t, parity p):
//   P1: barrier+vm8; read A(p,0) frags + B(p,0) c0/c1; stage A(t+1,kh1); mfma c0,c1 (k0)
//   P2:              read B(p,0) c2/c3;                stage B(t+1,kh1); mfma c2,c3 (k0)
//   P3: barrier+vm8; read A(p,1) frags + B(p,1) c0/c1; stage A(t+2,kh0); mfma c0,c1 (k1)
//   P4:              read B(p,1) c2/c3;                stage B(t+2,kh0); mfma c2,c3 (k1)
// Each stage targets a region whose last reads precede the most recent barrier.
#define QKV_TILE(TT, VM1, VM3, S12, S34) {                                         \
    const short* Ar = smem + ((TT) & 1) * 16384;                                   \
    const short* Br = smem + 32768 + ((TT) & 1) * 16384;                           \
    VMWAIT(VM1);                                                                   \
    __builtin_amdgcn_s_barrier();                                                  \
    SCHEDB();                                                                      \
    bf16x8 af[8], b0, b1;                                                          \
    _Pragma("unroll") for (int i = 0; i < 8; ++i)                                  \
      af[i] = *(const bf16x8*)&Ar[(wm + i * 16 + lr) * 32 + l4 * 8];               \
    b0 = *(const bf16x8*)&Br[(wn +  0 + lr) * 32 + l4 * 8];                        \
    b1 = *(const bf16x8*)&Br[(wn + 16 + lr) * 32 + l4 * 8];                        \
    if (S12) stageA((TT) + 1, 1);                                                  \
    __builtin_amdgcn_s_setprio(1);                                                 \
    _Pragma("unroll") for (int i = 0; i < 8; ++i) {                                \
      acc[i][0] = MFMA16(af[i], b0, acc[i][0]);                                    \
      acc[i][1] = MFMA16(af[i], b1, acc[i][1]);                                    \
    }                                                                              \
    __builtin_amdgcn_s_setprio(0);                                                 \
    b0 = *(const bf16x8*)&Br[(wn + 32 + lr) * 32 + l4 * 8];                        \
    b1 = *(const bf16x8*)&Br[(wn + 48 + lr) * 32 + l4 * 8];                        \
    if (S12) stageB((TT) + 1, 1);                                                  \
    __builtin_amdgcn_s_setprio(1);                                                 \
    _Pragma("unroll") for (int i = 0; i < 8; ++i) {                                \
      acc[i][2] = MFMA16(af[i], b0, acc[i][2]);                                    \
      acc[i][3] = MFMA16(af[i], b1, acc[i][3]);                                    \
    }                                                                              \
    __builtin_amdgcn_s_setprio(0);                                                 \
    VMWAIT(VM3);                                                                   \
    __builtin_amdgcn_s_barrier();                                                  \
    SCHEDB();                                                                      \
    const short* Ar1 = Ar + 8192;                                                  \
    const short* Br1 = Br + 8192;                                                  \
    _Pragma("unroll") for (int i = 0; i < 8; ++i)                                  \
      af[i] = *(const bf16x8*)&Ar1[(wm + i * 16 + lr) * 32 + l4 * 8];              \
    b0 = *(const bf16x8*)&Br1[(wn +  0 + lr) * 32 + l4 * 8];                       \
    b1 = *(const bf16x8*)&Br1[(wn + 16 + lr) * 32 + l4 * 8];                       \
    if (S34) stageA((TT) + 2, 0);                                                  \
    __builtin_amdgcn_s_setprio(1);                                                 \
    _Pragma("unroll") for (int i = 0; i < 8; ++i) {                                \
      acc[i][0] = MFMA16(af[i], b0, acc[i][0]);                                    \
      acc[i][1] = MFMA16(af[i], b1, acc[i][1]);                                    \
    }                                                                              \
    __builtin_amdgcn_s_setprio(0);                                                 \
    b0 = *(const bf16x8*)&Br1[(wn + 32 + lr) * 32 + l4 * 8];                       \
    b1 = *(const bf16x8*)&Br1[(wn + 48 + lr) * 32 + l4 * 8];                       \
    if (S34) stageB((TT) + 2, 0);                                                  \
    __builtin_amdgcn_s_setprio(1);                                                 \
    _Pragma("unroll") for (int i = 0; i < 8; ++i) {                                \
      acc[i][2] = MFMA16(af[i], b0, acc[i][2]);                                    \
      acc[i][3] = MFMA16(af[i], b1, acc[i][3]);                                    \
    }                                                                              \
    __builtin_amdgcn_s_setprio(0);                                                 \
  }

__global__ __launch_bounds__(512, 2)
void gemm_qkv(const short* __restrict__ A, const short* __restrict__ B,
              short* __restrict__ Qb, short* __restrict__ Kb, short* __restrict__ Vtb,
              const float* __restrict__ cosb, const float* __restrict__ sinb) {
  const int K = 4096;
  extern __shared__ __align__(16) short smem[];   // 131072 B
  const int bn = blockIdx.x * 256;
  const int bm = blockIdx.y * 256;
  const int t = threadIdx.x;
  const int lane = t & 63;
  const int w = t >> 6;
  const int wm = (w >> 2) * 128;   // 2 M wave-groups
  const int wn = (w & 3) * 64;     // 4 N wave-groups
  const int lr = lane & 15;
  const int l4 = lane >> 4;

  f32x4 acc[8][4] = {};

  // staging geometry: region = 256 rows x 32 shorts; wave w owns 1KB slots w and 8+w
  const int srow0 = w * 16 + (lane >> 2);
  const int srow1 = (8 + w) * 16 + (lane >> 2);
  const int sch   = (lane & 3) * 8;
  const size_t ga0 = (size_t)(bm + srow0) * K + sch;
  const size_t ga1 = (size_t)(bm + srow1) * K + sch;
  const size_t gb0 = (size_t)(bn + srow0) * K + sch;
  const size_t gb1 = (size_t)(bn + srow1) * K + sch;
  const int ldl0 = w * 512 + lane * 8;
  const int ldl1 = (8 + w) * 512 + lane * 8;

  auto stageA = [&](int kt, int kh) {
    const int ko = kt * 64 + kh * 32;
    short* rb = smem + (kt & 1) * 16384 + kh * 8192;
    gld16(A + ga0 + ko, rb + ldl0);
    gld16(A + ga1 + ko, rb + ldl1);
  };
  auto stageB = [&](int kt, int kh) {
    const int ko = kt * 64 + kh * 32;
    short* rb = smem + 32768 + (kt & 1) * 16384 + kh * 8192;
    gld16(B + gb0 + ko, rb + ldl0);
    gld16(B + gb1 + ko, rb + ldl1);
  };

  // prologue: tile0 complete + tile1 k0 (12 loads in flight)
  stageA(0, 0); stageB(0, 0);
  stageA(0, 1); stageB(0, 1);
  stageA(1, 0); stageB(1, 0);

  for (int kt = 0; kt < 62; ++kt) QKV_TILE(kt, 8, 8, 1, 1);
  QKV_TILE(62, 8, 8, 1, 0);
  QKV_TILE(63, 4, 0, 0, 0);

  // ---------------- epilogue ----------------
  const int cr = (lane >> 4) << 2;
  const int cc = lane & 15;
  const int region = (bn >= 5120) ? 2 : (bn >= 4096 ? 1 : 0);

  if (region < 2) {
    // RoPE: waves with (wn&64)==0 hold the rope half [0,64) of a head;
    // pairs (c, c+32) are acc[i][j] / acc[i][j+2], j in {0,1}.
    if ((wn & 64) == 0) {
#pragma unroll
      for (int i = 0; i < 8; ++i) {
#pragma unroll
        for (int r = 0; r < 4; ++r) {
          int srow = bm + wm + i * 16 + cr + r;
#pragma unroll
          for (int j = 0; j < 2; ++j) {
            int c = j * 16 + cc;
            float cv = cosb[srow * 64 + c];
            float sv = sinb[srow * 64 + c];
            float x1 = acc[i][j][r], x2 = acc[i][j + 2][r];
            acc[i][j][r]     = x1 * cv - x2 * sv;
            acc[i][j + 2][r] = x2 * cv + x1 * sv;
          }
        }
      }
    }
#pragma unroll
    for (int i = 0; i < 8; ++i)
#pragma unroll
      for (int j = 0; j < 4; ++j) {
        int row = bm + wm + i * 16 + cr;
        int col = bn + wn + j * 16 + cc;
#pragma unroll
        for (int r = 0; r < 4; ++r) {
          short v = f2bf(acc[i][j][r]);
          if (region == 0) Qb[(size_t)(row + r) * 4096 + col] = v;
          else             Kb[(size_t)(row + r) * 1024 + (col - 4096)] = v;
        }
      }
  } else {
    // V: transpose through LDS in two 128-row passes, coalesced 16B stores
    __syncthreads();
#pragma unroll
    for (int h = 0; h < 2; ++h) {
      if ((wm >> 7) == h) {
#pragma unroll
        for (int i = 0; i < 8; ++i)
#pragma unroll
          for (int j = 0; j < 4; ++j) {
            int lc = wn + j * 16 + cc;
            int lrow = i * 16 + cr;
#pragma unroll
            for (int r = 0; r < 4; ++r)
              smem[lc * 132 + lrow + r] = f2bf(acc[i][j][r]);
          }
      }
      __syncthreads();
      int colx = t >> 1;
      int off = (t & 1) * 64;
      short* dst = Vtb + (size_t)(bn - 5120 + colx) * 2048 + bm + h * 128 + off;
#pragma unroll
      for (int c8 = 0; c8 < 8; ++c8)
        *(bf16x8*)(dst + c8 * 8) = *(const bf16x8*)&smem[colx * 132 + off + c8 * 8];
      if (h == 0) __syncthreads();
    }
  }
}

// ---------------- output GEMM: BK=64 double-buffered, swizzled LDS ----------------
__global__ __launch_bounds__(256, 2)
void gemm_out(const short* __restrict__ A, const short* __restrict__ B,
              float* __restrict__ C) {
  const int K = 4096, N = 4096;
  __shared__ short smem[32768];          // 64 KB: 2 x (A 16KB | B 16KB)
  const int bn = blockIdx.x * 128;
  const int bm = blockIdx.y * 128;
  const int t = threadIdx.x;
  const int lane = t & 63;
  const int wave = t >> 6;
  const int wm = (wave >> 1) * 64;
  const int wn = (wave & 1) * 64;
  const int lr = lane & 15;
  const int lk3 = lane >> 4;             // k-chunk 0..3

  f32x4 acc[4][4] = {};

  const int srow = t >> 3;               // 0..31
  const int sch = (t & 7) ^ ((srow & 1) << 2);   // source-permuted chunk
  const size_t ab = (size_t)(bm + srow) * K + sch * 8;
  const size_t bb = (size_t)(bn + srow) * K + sch * 8;

  auto stage = [&](int k0, int b) {
    short* dst = smem + b * 16384 + t * 8;
#pragma unroll
    for (int p = 0; p < 4; ++p) {
      gld16(A + ab + k0 + (size_t)(p * 32) * K, dst + p * 2048);
      gld16(B + bb + k0 + (size_t)(p * 32) * K, dst + 8192 + p * 2048);
    }
  };

  stage(0, 0);
  for (int it = 0; it < 64; ++it) {
    __syncthreads();
    if (it + 1 < 64) stage((it + 1) * 64, (it + 1) & 1);
    const short* Asb = smem + (it & 1) * 16384;
    const short* Bsb = Asb + 8192;
#pragma unroll
    for (int h = 0; h < 2; ++h) {
      bf16x8 af[4], bfr[4];
#pragma unroll
      for (int i = 0; i < 4; ++i) {
        int row = wm + i * 16 + lr;
        af[i] = *(const bf16x8*)&Asb[row * 64 + (((h * 4 + lk3) ^ ((row & 1) << 2)) * 8)];
      }
#pragma unroll
      for (int j = 0; j < 4; ++j) {
        int row = wn + j * 16 + lr;
        bfr[j] = *(const bf16x8*)&Bsb[row * 64 + (((h * 4 + lk3) ^ ((row & 1) << 2)) * 8)];
      }
#pragma unroll
      for (int i = 0; i < 4; ++i)
#pragma unroll
        for (int j = 0; j < 4; ++j)
          acc[i][j] = __builtin_amdgcn_mfma_f32_16x16x32_bf16(af[i], bfr[j], acc[i][j], 0, 0, 0);
    }
  }

  const int cr = (lane >> 4) << 2;
  const int cc = lane & 15;
#pragma unroll
  for (int i = 0; i < 4; ++i)
#pragma unroll
    for (int j = 0; j < 4; ++j) {
      int row = bm + wm + i * 16 + cr;
      int col = bn + wn + j * 16 + cc;
#pragma unroll
      for (int r = 0; r < 4; ++r)
        C[(size_t)(row + r) * N + col] = acc[i][j][r];
    }
}

// ---------------- flash attention, S^T form, max-free softmax ----------------
__global__ __launch_bounds__(256, 2)
void attn_kernel(const short* __restrict__ Q, const short* __restrict__ Kg,
                 const short* __restrict__ Vg, const float* __restrict__ sinks,
                 short* __restrict__ O) {
  __shared__ short lds[32768];   // 64 KB: buf0 [Ks 8192 | Vs 8192], buf1 same
  const int h = blockIdx.x;
  const int qt = 15 - blockIdx.y;
  const int q0 = qt * 128;
  const int kvh = h >> 2;
  const int t = threadIdx.x;
  const int lane = t & 63;
  const int w = t >> 6;
  const int l31 = lane & 31;
  const int l7 = lane & 7;
  const bool qh = lane >= 32;
  const int q5 = qh ? 1 : 0;
  const int nkt = 2 * qt + 2;

  const int kch = (t & 15) ^ ((t >> 4) & 7);
  const short* kgb = Kg + (size_t)(t >> 4) * 1024 + kvh * 128 + kch * 8;
  const int vch = (t & 7) ^ ((t >> 3) & 7);
  const short* vgb = Vg + (size_t)(kvh * 128 + (t >> 3)) * 2048 + vch * 8;

  auto stage = [&](int kt, int b) {
    short* kl = lds + b * 16384 + t * 8;
    short* vl = lds + b * 16384 + 8192 + t * 8;
    const short* kg = kgb + (size_t)kt * 64 * 1024;
    const short* vg = vgb + kt * 64;
#pragma unroll
    for (int c = 0; c < 4; ++c) {
      gld16(kg + (size_t)c * 16 * 1024, kl + c * 2048);
      gld16(vg + (size_t)c * 32 * 2048, vl + c * 2048);
    }
  };

  const short* qp = Q + (size_t)(q0 + w * 32 + l31) * 4096 + h * 128 + q5 * 8;
  bf16x8 qf[8];
#pragma unroll
  for (int st = 0; st < 8; ++st) qf[st] = *(const bf16x8*)(qp + st * 16);

  union { short s[8]; bf16x8 v; } ones;
#pragma unroll
  for (int i = 0; i < 8; ++i) ones.s[i] = (short)0x3F80;

  f32x16 acc[4] = {};
  f32x16 lacc = {};

  stage(0, 0);
  const int qg = q0 + w * 32 + l31;
  const float ce = 0.12751743f;   // (1/sqrt(128)) * log2(e)

  for (int kt = 0; kt < nkt; ++kt) {
    const int b = kt & 1;
    __syncthreads();
    if (kt + 1 < nkt) stage(kt + 1, b ^ 1);
    const short* Ks = lds + b * 16384;
    const short* Vs = Ks + 8192;

    f32x16 sa0 = {}, sa1 = {};
#pragma unroll
    for (int st = 0; st < 8; ++st) {
      const int cp = ((st * 2 + q5) ^ l7) * 8;
      bf16x8 k0 = *(const bf16x8*)(Ks + (l31) * 128 + cp);
      bf16x8 k1 = *(const bf16x8*)(Ks + (32 + l31) * 128 + cp);
      sa0 = __builtin_amdgcn_mfma_f32_32x32x16_bf16(k0, qf[st], sa0, 0, 0, 0);
      sa1 = __builtin_amdgcn_mfma_f32_32x32x16_bf16(k1, qf[st], sa1, 0, 0, 0);
    }

    if (kt >= 2 * qt) {
      const int kb0 = kt * 64 + q5 * 4;
#pragma unroll
      for (int r = 0; r < 16; ++r) {
        int kg0 = kb0 + ((r >> 2) << 3) + (r & 3);
        float s0 = (kg0 <= qg) ? sa0[r] * ce : -INFINITY;
        float s1 = (kg0 + 32 <= qg) ? sa1[r] * ce : -INFINITY;
        sa0[r] = __builtin_amdgcn_exp2f(s0);
        sa1[r] = __builtin_amdgcn_exp2f(s1);
      }
    } else {
#pragma unroll
      for (int r = 0; r < 16; ++r) {
        sa0[r] = __builtin_amdgcn_exp2f(sa0[r] * ce);
        sa1[r] = __builtin_amdgcn_exp2f(sa1[r] * ce);
      }
    }

#pragma unroll
    for (int s = 0; s < 4; ++s) {
      const f32x16& S = (s & 2) ? sa1 : sa0;
      float a0, a1, a2, a3, b0, b1, b2, b3;
      if (s & 1) {
        a0 = qh ? S[12] : S[8];  a1 = qh ? S[13] : S[9];
        a2 = qh ? S[14] : S[10]; a3 = qh ? S[15] : S[11];
        b0 = qh ? S[8]  : S[12]; b1 = qh ? S[9]  : S[13];
        b2 = qh ? S[10] : S[14]; b3 = qh ? S[11] : S[15];
      } else {
        a0 = qh ? S[4] : S[0]; a1 = qh ? S[5] : S[1];
        a2 = qh ? S[6] : S[2]; a3 = qh ? S[7] : S[3];
        b0 = qh ? S[0] : S[4]; b1 = qh ? S[1] : S[5];
        b2 = qh ? S[2] : S[6]; b3 = qh ? S[3] : S[7];
      }
      unsigned d0 = pack_bf2(a0, a1), d1 = pack_bf2(a2, a3);
      unsigned e0 = pack_bf2(b0, b1), e1 = pack_bf2(b2, b3);
      unsigned r0 = (unsigned)__shfl_xor((int)e0, 32, 64);
      unsigned r1 = (unsigned)__shfl_xor((int)e1, 32, 64);
      union { unsigned u[4]; bf16x8 v; } P;
      P.u[0] = qh ? r0 : d0;  P.u[1] = qh ? r1 : d1;
      P.u[2] = qh ? d0 : r0;  P.u[3] = qh ? d1 : r1;

      lacc = __builtin_amdgcn_mfma_f32_32x32x16_bf16(ones.v, P.v, lacc, 0, 0, 0);
#pragma unroll
      for (int m = 0; m < 4; ++m) {
        bf16x8 vf = *(const bf16x8*)(Vs + (m * 32 + l31) * 64 + (((s * 2 + q5) ^ l7) * 8));
        acc[m] = __builtin_amdgcn_mfma_f32_32x32x16_bf16(vf, P.v, acc[m], 0, 0, 0);
      }
    }
  }

  float denom = lacc[0] + __builtin_amdgcn_exp2f(sinks[h] * 1.4426950f);
  float rinv = 1.0f / denom;

  __syncthreads();
#pragma unroll
  for (int m = 0; m < 4; ++m) {
#pragma unroll
    for (int r = 0; r < 16; ++r) {
      int d = m * 32 + ((r >> 2) << 3) + q5 * 4 + (r & 3);
      int ql = w * 32 + l31;
      lds[ql * 128 + (((d >> 3) ^ l7) << 3) + (d & 7)] = f2bf(acc[m][r] * rinv);
    }
  }
  __syncthreads();
  const int qrow = t >> 1;
  const int half = (t & 1) * 8;
  short* ob = O + (size_t)(q0 + qrow) * 4096 + h * 128;
#pragma unroll
  for (int cc = 0; cc < 8; ++cc) {
    int chunk = half + cc;
    bf16x8 v = *(const bf16x8*)&lds[qrow * 128 + ((chunk ^ (qrow & 7)) << 3)];
    *(bf16x8*)(ob + chunk * 8) = v;
  }
}

// ---------------- host ----------------
extern "C" void kernel_launch(void* const* d_in, const int* in_sizes, int n_in,
                              void* d_out, int out_size, void* d_ws, size_t ws_size,
                              hipStream_t stream) {
  const float* hs    = (const float*)d_in[0];
  const float* cosb  = (const float*)d_in[1];
  const float* sinb  = (const float*)d_in[2];
  const float* Wq    = (const float*)d_in[4];
  const float* Wk    = (const float*)d_in[5];
  const float* Wv    = (const float*)d_in[6];
  const float* Wo    = (const float*)d_in[7];
  const float* sinks = (const float*)d_in[8];
  float* out = (float*)d_out;

  static bool attr_done = false;
  if (!attr_done) {
    hipFuncSetAttribute(reinterpret_cast<const void*>(&gemm_qkv),
                        hipFuncAttributeMaxDynamicSharedMemorySize, 131072);
    attr_done = true;
  }

  char* ws = (char*)d_ws;
  short* Xb    = (short*)ws;                    // 16.78 MB  [2048][4096]
  short* Wqkvt = (short*)(ws + 16777216);       // 50.33 MB  [6144][4096]
  short* Qb    = (short*)(ws + 67108864);       // 16.78 MB  [2048][4096]
  short* Kb    = (short*)(ws + 83886080);       //  4.19 MB  [2048][1024]
  short* Vtb   = (short*)(ws + 88080384);       //  4.19 MB  [1024][2048]
  short* Ab    = Xb;                            // alias: X dead after qkv GEMM
  short* Wot   = Wqkvt;                         // alias: dead after qkv GEMM

  cvt_f32_bf16<<<8192, 256, 0, stream>>>(hs, Xb, 2097152);
  transpose_to_bf16<<<dim3(128, 128), 256, 0, stream>>>(Wq, Wqkvt, 4096, 4096);
  transpose_to_bf16<<<dim3(32, 128), 256, 0, stream>>>(Wk, Wqkvt + (size_t)4096 * 4096, 4096, 1024);
  transpose_to_bf16<<<dim3(32, 128), 256, 0, stream>>>(Wv, Wqkvt + (size_t)5120 * 4096, 4096, 1024);

  gemm_qkv<<<dim3(24, 8), 512, 131072, stream>>>(Xb, Wqkvt, Qb, Kb, Vtb, cosb, sinb);

  transpose_to_bf16<<<dim3(128, 128), 256, 0, stream>>>(Wo, Wot, 4096, 4096);

  attn_kernel<<<dim3(32, 16), 256, 0, stream>>>(Qb, Kb, Vtb, sinks, Ab);

  gemm_out<<<dim3(32, 16), 256, 0, stream>>>(Ab, Wot, out);
}

// Round 2
// 461.166 us; speedup vs baseline: 1.0548x; 1.0301x over previous
//
#include <hip/hip_runtime.h>
#include <hip/hip_bf16.h>
#include <cstdint>
#include <cstddef>

#define S_LEN 2048
#define NHEADS 32
#define NKVH   8
#define HDIM   128

using bf16x8 = __attribute__((ext_vector_type(8))) short;
using f32x4  = __attribute__((ext_vector_type(4))) float;
using f32x16 = __attribute__((ext_vector_type(16))) float;

__device__ __forceinline__ short f2bf(float f) {
  union { float f; unsigned u; } a; a.f = f;
  unsigned u = a.u;
  unsigned r = u + 0x7fffu + ((u >> 16) & 1u);   // RNE
  return (short)(r >> 16);
}
__device__ __forceinline__ unsigned pack_bf2(float lo, float hi) {
  union { float f; unsigned u; } a, b; a.f = lo; b.f = hi;
  return __builtin_amdgcn_perm(b.u, a.u, 0x07060302);
}

// async 16B global -> LDS (wave-uniform base + lane*16 on HW)
__device__ __forceinline__ void gld16(const void* g, void* l) {
  __builtin_amdgcn_global_load_lds((__attribute__((address_space(1))) void*)(void*)g,
                                   (__attribute__((address_space(3))) void*)l, 16, 0, 0);
}

#define VMWAIT(N) asm volatile("s_waitcnt vmcnt(" #N ")" ::: "memory")
#define SCHEDB()  __builtin_amdgcn_sched_barrier(0)
#define MFMA16(a, b, c) __builtin_amdgcn_mfma_f32_16x16x32_bf16((a), (b), (c), 0, 0, 0)

// ---------------- fp32 -> bf16 elementwise (x4 vectorized) ----------------
__global__ void cvt_f32_bf16(const float* __restrict__ x, short* __restrict__ y, int n4) {
  int i = blockIdx.x * blockDim.x + threadIdx.x;
  if (i >= n4) return;
  float4 v = reinterpret_cast<const float4*>(x)[i];
  short4 o;
  o.x = f2bf(v.x); o.y = f2bf(v.y); o.z = f2bf(v.z); o.w = f2bf(v.w);
  reinterpret_cast<short4*>(y)[i] = o;
}

// ------------- transpose + convert: W[K][N] fp32 -> Wt[N][K] bf16 -------------
__global__ __launch_bounds__(256)
void transpose_to_bf16(const float* __restrict__ W, short* __restrict__ Wt,
                       int K, int N) {
  __shared__ float tile[32 * 33];
  const int bn = blockIdx.x * 32, bk = blockIdx.y * 32;
  const int t = threadIdx.x;
  const int c4 = t & 7, kr = t >> 3;
  float4 v = *(const float4*)&W[(size_t)(bk + kr) * N + bn + c4 * 4];
  tile[kr * 33 + c4 * 4 + 0] = v.x;
  tile[kr * 33 + c4 * 4 + 1] = v.y;
  tile[kr * 33 + c4 * 4 + 2] = v.z;
  tile[kr * 33 + c4 * 4 + 3] = v.w;
  __syncthreads();
  const int k4 = t & 7, nr = t >> 3;
  short4 o;
  o.x = f2bf(tile[(k4 * 4 + 0) * 33 + nr]);
  o.y = f2bf(tile[(k4 * 4 + 1) * 33 + nr]);
  o.z = f2bf(tile[(k4 * 4 + 2) * 33 + nr]);
  o.w = f2bf(tile[(k4 * 4 + 3) * 33 + nr]);
  *(short4*)&Wt[(size_t)(bn + nr) * K + bk + k4 * 4] = o;
}

// ---------------- fused QKV GEMM + RoPE epilogue ----------------
// 256x256 tile, BK=64, 8 waves (2Mx4N), per-wave 128x64 output.
// LDS 128KB: A/B double-buffered, each K-tile split into two 16KB K-half
// regions (256 rows x 32 shorts).
//
// Bank-conflict-free chunk swizzle (T2): LDS slot (row, c') holds global
// k-chunk c' ^ ((row>>1)&3). Reads use chunk l4 ^ ((row>>1)&3); within a
// 16-lane LDS group (l4 const, lr=0..15) this spreads over all 8
// (row-parity x chunk) 4-bank segments -> 2 lanes/segment = minimum.
// Staging keeps global_load_lds linear dest and pre-swizzles the global
// source chunk: (lane&3) ^ ((lane>>3)&3) -- same 64B row, coalescing intact.
//
// 4 phases per K-tile; raw s_barrier + counted vmcnt(8) at phases 1 and 3.
#define QKV_TILE(TT, VM1, VM3, S12, S34) {                                         \
    const short* Ar = smem + ((TT) & 1) * 16384;                                   \
    const short* Br = smem + 32768 + ((TT) & 1) * 16384;                           \
    VMWAIT(VM1);                                                                   \
    __builtin_amdgcn_s_barrier();                                                  \
    SCHEDB();                                                                      \
    bf16x8 af[8], b0, b1;                                                          \
    _Pragma("unroll") for (int i = 0; i < 8; ++i)                                  \
      af[i] = *(const bf16x8*)&Ar[(wm + i * 16 + lr) * 32 + csw];                  \
    b0 = *(const bf16x8*)&Br[(wn +  0 + lr) * 32 + csw];                           \
    b1 = *(const bf16x8*)&Br[(wn + 16 + lr) * 32 + csw];                           \
    if (S12) stageA((TT) + 1, 1);                                                  \
    __builtin_amdgcn_s_setprio(1);                                                 \
    _Pragma("unroll") for (int i = 0; i < 8; ++i) {                                \
      acc[i][0] = MFMA16(af[i], b0, acc[i][0]);                                    \
      acc[i][1] = MFMA16(af[i], b1, acc[i][1]);                                    \
    }                                                                              \
    __builtin_amdgcn_s_setprio(0);                                                 \
    b0 = *(const bf16x8*)&Br[(wn + 32 + lr) * 32 + csw];                           \
    b1 = *(const bf16x8*)&Br[(wn + 48 + lr) * 32 + csw];                           \
    if (S12) stageB((TT) + 1, 1);                                                  \
    __builtin_amdgcn_s_setprio(1);                                                 \
    _Pragma("unroll") for (int i = 0; i < 8; ++i) {                                \
      acc[i][2] = MFMA16(af[i], b0, acc[i][2]);                                    \
      acc[i][3] = MFMA16(af[i], b1, acc[i][3]);                                    \
    }                                                                              \
    __builtin_amdgcn_s_setprio(0);                                                 \
    VMWAIT(VM3);                                                                   \
    __builtin_amdgcn_s_barrier();                                                  \
    SCHEDB();                                                                      \
    const short* Ar1 = Ar + 8192;                                                  \
    const short* Br1 = Br + 8192;                                                  \
    _Pragma("unroll") for (int i = 0; i < 8; ++i)                                  \
      af[i] = *(const bf16x8*)&Ar1[(wm + i * 16 + lr) * 32 + csw];                 \
    b0 = *(const bf16x8*)&Br1[(wn +  0 + lr) * 32 + csw];                          \
    b1 = *(const bf16x8*)&Br1[(wn + 16 + lr) * 32 + csw];                          \
    if (S34) stageA((TT) + 2, 0);                                                  \
    __builtin_amdgcn_s_setprio(1);                                                 \
    _Pragma("unroll") for (int i = 0; i < 8; ++i) {                                \
      acc[i][0] = MFMA16(af[i], b0, acc[i][0]);                                    \
      acc[i][1] = MFMA16(af[i], b1, acc[i][1]);                                    \
    }                                                                              \
    __builtin_amdgcn_s_setprio(0);                                                 \
    b0 = *(const bf16x8*)&Br1[(wn + 32 + lr) * 32 + csw];                          \
    b1 = *(const bf16x8*)&Br1[(wn + 48 + lr) * 32 + csw];                          \
    if (S34) stageB((TT) + 2, 0);                                                  \
    __builtin_amdgcn_s_setprio(1);                                                 \
    _Pragma("unroll") for (int i = 0; i < 8; ++i) {                                \
      acc[i][2] = MFMA16(af[i], b0, acc[i][2]);                                    \
      acc[i][3] = MFMA16(af[i], b1, acc[i][3]);                                    \
    }                                                                              \
    __builtin_amdgcn_s_setprio(0);                                                 \
  }

__global__ __launch_bounds__(512, 2)
void gemm_qkv(const short* __restrict__ A, const short* __restrict__ B,
              short* __restrict__ Qb, short* __restrict__ Kb, short* __restrict__ Vtb,
              const float* __restrict__ cosb, const float* __restrict__ sinb) {
  const int K = 4096;
  extern __shared__ __align__(16) short smem[];   // 131072 B
  const int bn = blockIdx.x * 256;
  const int bm = blockIdx.y * 256;
  const int t = threadIdx.x;
  const int lane = t & 63;
  const int w = t >> 6;
  const int wm = (w >> 2) * 128;   // 2 M wave-groups
  const int wn = (w & 3) * 64;     // 4 N wave-groups
  const int lr = lane & 15;
  const int l4 = lane >> 4;
  // read-side swizzled chunk offset (shorts): l4 ^ ((row>>1)&3), row bits from lr
  const int csw = ((l4 ^ ((lr >> 1) & 3)) * 8);

  f32x4 acc[8][4] = {};

  // staging geometry: region = 256 rows x 32 shorts; wave w owns 1KB slots w and 8+w
  const int srow0 = w * 16 + (lane >> 2);
  const int srow1 = (8 + w) * 16 + (lane >> 2);
  // pre-swizzled global source chunk so linear LDS dest yields swizzled layout
  const int sch   = ((lane & 3) ^ ((lane >> 3) & 3)) * 8;
  const size_t ga0 = (size_t)(bm + srow0) * K + sch;
  const size_t ga1 = (size_t)(bm + srow1) * K + sch;
  const size_t gb0 = (size_t)(bn + srow0) * K + sch;
  const size_t gb1 = (size_t)(bn + srow1) * K + sch;
  const int ldl0 = w * 512 + lane * 8;
  const int ldl1 = (8 + w) * 512 + lane * 8;

  auto stageA = [&](int kt, int kh) {
    const int ko = kt * 64 + kh * 32;
    short* rb = smem + (kt & 1) * 16384 + kh * 8192;
    gld16(A + ga0 + ko, rb + ldl0);
    gld16(A + ga1 + ko, rb + ldl1);
  };
  auto stageB = [&](int kt, int kh) {
    const int ko = kt * 64 + kh * 32;
    short* rb = smem + 32768 + (kt & 1) * 16384 + kh * 8192;
    gld16(B + gb0 + ko, rb + ldl0);
    gld16(B + gb1 + ko, rb + ldl1);
  };

  // prologue: tile0 complete + tile1 k0 (12 loads in flight)
  stageA(0, 0); stageB(0, 0);
  stageA(0, 1); stageB(0, 1);
  stageA(1, 0); stageB(1, 0);

  for (int kt = 0; kt < 62; ++kt) QKV_TILE(kt, 8, 8, 1, 1);
  QKV_TILE(62, 8, 8, 1, 0);
  QKV_TILE(63, 4, 0, 0, 0);

  // ---------------- epilogue ----------------
  const int cr = (lane >> 4) << 2;
  const int cc = lane & 15;
  const int region = (bn >= 5120) ? 2 : (bn >= 4096 ? 1 : 0);

  if (region < 2) {
    // RoPE: waves with (wn&64)==0 hold the rope half [0,64) of a head;
    // pairs (c, c+32) are acc[i][j] / acc[i][j+2], j in {0,1}.
    if ((wn & 64) == 0) {
#pragma unroll
      for (int i = 0; i < 8; ++i) {
#pragma unroll
        for (int r = 0; r < 4; ++r) {
          int srow = bm + wm + i * 16 + cr + r;
#pragma unroll
          for (int j = 0; j < 2; ++j) {
            int c = j * 16 + cc;
            float cv = cosb[srow * 64 + c];
            float sv = sinb[srow * 64 + c];
            float x1 = acc[i][j][r], x2 = acc[i][j + 2][r];
            acc[i][j][r]     = x1 * cv - x2 * sv;
            acc[i][j + 2][r] = x2 * cv + x1 * sv;
          }
        }
      }
    }
#pragma unroll
    for (int i = 0; i < 8; ++i)
#pragma unroll
      for (int j = 0; j < 4; ++j) {
        int row = bm + wm + i * 16 + cr;
        int col = bn + wn + j * 16 + cc;
#pragma unroll
        for (int r = 0; r < 4; ++r) {
          short v = f2bf(acc[i][j][r]);
          if (region == 0) Qb[(size_t)(row + r) * 4096 + col] = v;
          else             Kb[(size_t)(row + r) * 1024 + (col - 4096)] = v;
        }
      }
  } else {
    // V: transpose through LDS in two 128-row passes, coalesced 16B stores
    __syncthreads();
#pragma unroll
    for (int h = 0; h < 2; ++h) {
      if ((wm >> 7) == h) {
#pragma unroll
        for (int i = 0; i < 8; ++i)
#pragma unroll
          for (int j = 0; j < 4; ++j) {
            int lc = wn + j * 16 + cc;
            int lrow = i * 16 + cr;
#pragma unroll
            for (int r = 0; r < 4; ++r)
              smem[lc * 132 + lrow + r] = f2bf(acc[i][j][r]);
          }
      }
      __syncthreads();
      int colx = t >> 1;
      int off = (t & 1) * 64;
      short* dst = Vtb + (size_t)(bn - 5120 + colx) * 2048 + bm + h * 128 + off;
#pragma unroll
      for (int c8 = 0; c8 < 8; ++c8)
        *(bf16x8*)(dst + c8 * 8) = *(const bf16x8*)&smem[colx * 132 + off + c8 * 8];
      if (h == 0) __syncthreads();
    }
  }
}

// ---------------- output GEMM: BK=64 double-buffered, swizzled LDS ----------------
// Same T2 fix: rows are 64 shorts (128B, bank base 0 for every row), so the
// chunk swizzle must use (row&7) to spread a 16-lane group across all 8
// 4-bank segments. Staging pre-swizzles the global source chunk to match.
__global__ __launch_bounds__(256, 2)
void gemm_out(const short* __restrict__ A, const short* __restrict__ B,
              float* __restrict__ C) {
  const int K = 4096, N = 4096;
  __shared__ short smem[32768];          // 64 KB: 2 x (A 16KB | B 16KB)
  const int bn = blockIdx.x * 128;
  const int bm = blockIdx.y * 128;
  const int t = threadIdx.x;
  const int lane = t & 63;
  const int wave = t >> 6;
  const int wm = (wave >> 1) * 64;
  const int wn = (wave & 1) * 64;
  const int lr = lane & 15;
  const int lk3 = lane >> 4;             // k-chunk 0..3

  f32x4 acc[4][4] = {};

  const int srow = t >> 3;               // 0..31
  const int sch = (t & 7) ^ ((t >> 3) & 7);   // source-permuted chunk
  const size_t ab = (size_t)(bm + srow) * K + sch * 8;
  const size_t bb = (size_t)(bn + srow) * K + sch * 8;

  auto stage = [&](int k0, int b) {
    short* dst = smem + b * 16384 + t * 8;
#pragma unroll
    for (int p = 0; p < 4; ++p) {
      gld16(A + ab + k0 + (size_t)(p * 32) * K, dst + p * 2048);
      gld16(B + bb + k0 + (size_t)(p * 32) * K, dst + 8192 + p * 2048);
    }
  };

  stage(0, 0);
  for (int it = 0; it < 64; ++it) {
    __syncthreads();
    if (it + 1 < 64) stage((it + 1) * 64, (it + 1) & 1);
    const short* Asb = smem + (it & 1) * 16384;
    const short* Bsb = Asb + 8192;
#pragma unroll
    for (int h = 0; h < 2; ++h) {
      bf16x8 af[4], bfr[4];
#pragma unroll
      for (int i = 0; i < 4; ++i) {
        int row = wm + i * 16 + lr;
        af[i] = *(const bf16x8*)&Asb[row * 64 + (((h * 4 + lk3) ^ (lr & 7)) * 8)];
      }
#pragma unroll
      for (int j = 0; j < 4; ++j) {
        int row = wn + j * 16 + lr;
        bfr[j] = *(const bf16x8*)&Bsb[row * 64 + (((h * 4 + lk3) ^ (lr & 7)) * 8)];
      }
#pragma unroll
      for (int i = 0; i < 4; ++i)
#pragma unroll
        for (int j = 0; j < 4; ++j)
          acc[i][j] = __builtin_amdgcn_mfma_f32_16x16x32_bf16(af[i], bfr[j], acc[i][j], 0, 0, 0);
    }
  }

  const int cr = (lane >> 4) << 2;
  const int cc = lane & 15;
#pragma unroll
  for (int i = 0; i < 4; ++i)
#pragma unroll
    for (int j = 0; j < 4; ++j) {
      int row = bm + wm + i * 16 + cr;
      int col = bn + wn + j * 16 + cc;
#pragma unroll
      for (int r = 0; r < 4; ++r)
        C[(size_t)(row + r) * N + col] = acc[i][j][r];
    }
}

// ---------------- flash attention, S^T form, max-free softmax ----------------
__global__ __launch_bounds__(256, 2)
void attn_kernel(const short* __restrict__ Q, const short* __restrict__ Kg,
                 const short* __restrict__ Vg, const float* __restrict__ sinks,
                 short* __restrict__ O) {
  __shared__ short lds[32768];   // 64 KB: buf0 [Ks 8192 | Vs 8192], buf1 same
  const int h = blockIdx.x;
  const int qt = 15 - blockIdx.y;
  const int q0 = qt * 128;
  const int kvh = h >> 2;
  const int t = threadIdx.x;
  const int lane = t & 63;
  const int w = t >> 6;
  const int l31 = lane & 31;
  const int l7 = lane & 7;
  const bool qh = lane >= 32;
  const int q5 = qh ? 1 : 0;
  const int nkt = 2 * qt + 2;

  const int kch = (t & 15) ^ ((t >> 4) & 7);
  const short* kgb = Kg + (size_t)(t >> 4) * 1024 + kvh * 128 + kch * 8;
  const int vch = (t & 7) ^ ((t >> 3) & 7);
  const short* vgb = Vg + (size_t)(kvh * 128 + (t >> 3)) * 2048 + vch * 8;

  auto stage = [&](int kt, int b) {
    short* kl = lds + b * 16384 + t * 8;
    short* vl = lds + b * 16384 + 8192 + t * 8;
    const short* kg = kgb + (size_t)kt * 64 * 1024;
    const short* vg = vgb + kt * 64;
#pragma unroll
    for (int c = 0; c < 4; ++c) {
      gld16(kg + (size_t)c * 16 * 1024, kl + c * 2048);
      gld16(vg + (size_t)c * 32 * 2048, vl + c * 2048);
    }
  };

  const short* qp = Q + (size_t)(q0 + w * 32 + l31) * 4096 + h * 128 + q5 * 8;
  bf16x8 qf[8];
#pragma unroll
  for (int st = 0; st < 8; ++st) qf[st] = *(const bf16x8*)(qp + st * 16);

  union { short s[8]; bf16x8 v; } ones;
#pragma unroll
  for (int i = 0; i < 8; ++i) ones.s[i] = (short)0x3F80;

  f32x16 acc[4] = {};
  f32x16 lacc = {};

  stage(0, 0);
  const int qg = q0 + w * 32 + l31;
  const float ce = 0.12751743f;   // (1/sqrt(128)) * log2(e)

  for (int kt = 0; kt < nkt; ++kt) {
    const int b = kt & 1;
    __syncthreads();
    if (kt + 1 < nkt) stage(kt + 1, b ^ 1);
    const short* Ks = lds + b * 16384;
    const short* Vs = Ks + 8192;

    f32x16 sa0 = {}, sa1 = {};
#pragma unroll
    for (int st = 0; st < 8; ++st) {
      const int cp = ((st * 2 + q5) ^ l7) * 8;
      bf16x8 k0 = *(const bf16x8*)(Ks + (l31) * 128 + cp);
      bf16x8 k1 = *(const bf16x8*)(Ks + (32 + l31) * 128 + cp);
      sa0 = __builtin_amdgcn_mfma_f32_32x32x16_bf16(k0, qf[st], sa0, 0, 0, 0);
      sa1 = __builtin_amdgcn_mfma_f32_32x32x16_bf16(k1, qf[st], sa1, 0, 0, 0);
    }

    if (kt >= 2 * qt) {
      const int kb0 = kt * 64 + q5 * 4;
#pragma unroll
      for (int r = 0; r < 16; ++r) {
        int kg0 = kb0 + ((r >> 2) << 3) + (r & 3);
        float s0 = (kg0 <= qg) ? sa0[r] * ce : -INFINITY;
        float s1 = (kg0 + 32 <= qg) ? sa1[r] * ce : -INFINITY;
        sa0[r] = __builtin_amdgcn_exp2f(s0);
        sa1[r] = __builtin_amdgcn_exp2f(s1);
      }
    } else {
#pragma unroll
      for (int r = 0; r < 16; ++r) {
        sa0[r] = __builtin_amdgcn_exp2f(sa0[r] * ce);
        sa1[r] = __builtin_amdgcn_exp2f(sa1[r] * ce);
      }
    }

#pragma unroll
    for (int s = 0; s < 4; ++s) {
      const f32x16& S = (s & 2) ? sa1 : sa0;
      float a0, a1, a2, a3, b0, b1, b2, b3;
      if (s & 1) {
        a0 = qh ? S[12] : S[8];  a1 = qh ? S[13] : S[9];
        a2 = qh ? S[14] : S[10]; a3 = qh ? S[15] : S[11];
        b0 = qh ? S[8]  : S[12]; b1 = qh ? S[9]  : S[13];
        b2 = qh ? S[10] : S[14]; b3 = qh ? S[11] : S[15];
      } else {
        a0 = qh ? S[4] : S[0]; a1 = qh ? S[5] : S[1];
        a2 = qh ? S[6] : S[2]; a3 = qh ? S[7] : S[3];
        b0 = qh ? S[0] : S[4]; b1 = qh ? S[1] : S[5];
        b2 = qh ? S[2] : S[6]; b3 = qh ? S[3] : S[7];
      }
      unsigned d0 = pack_bf2(a0, a1), d1 = pack_bf2(a2, a3);
      unsigned e0 = pack_bf2(b0, b1), e1 = pack_bf2(b2, b3);
      unsigned r0 = (unsigned)__shfl_xor((int)e0, 32, 64);
      unsigned r1 = (unsigned)__shfl_xor((int)e1, 32, 64);
      union { unsigned u[4]; bf16x8 v; } P;
      P.u[0] = qh ? r0 : d0;  P.u[1] = qh ? r1 : d1;
      P.u[2] = qh ? d0 : r0;  P.u[3] = qh ? d1 : r1;

      lacc = __builtin_amdgcn_mfma_f32_32x32x16_bf16(ones.v, P.v, lacc, 0, 0, 0);
#pragma unroll
      for (int m = 0; m < 4; ++m) {
        bf16x8 vf = *(const bf16x8*)(Vs + (m * 32 + l31) * 64 + (((s * 2 + q5) ^ l7) * 8));
        acc[m] = __builtin_amdgcn_mfma_f32_32x32x16_bf16(vf, P.v, acc[m], 0, 0, 0);
      }
    }
  }

  float denom = lacc[0] + __builtin_amdgcn_exp2f(sinks[h] * 1.4426950f);
  float rinv = 1.0f / denom;

  __syncthreads();
#pragma unroll
  for (int m = 0; m < 4; ++m) {
#pragma unroll
    for (int r = 0; r < 16; ++r) {
      int d = m * 32 + ((r >> 2) << 3) + q5 * 4 + (r & 3);
      int ql = w * 32 + l31;
      lds[ql * 128 + (((d >> 3) ^ l7) << 3) + (d & 7)] = f2bf(acc[m][r] * rinv);
    }
  }
  __syncthreads();
  const int qrow = t >> 1;
  const int half = (t & 1) * 8;
  short* ob = O + (size_t)(q0 + qrow) * 4096 + h * 128;
#pragma unroll
  for (int cc = 0; cc < 8; ++cc) {
    int chunk = half + cc;
    bf16x8 v = *(const bf16x8*)&lds[qrow * 128 + ((chunk ^ (qrow & 7)) << 3)];
    *(bf16x8*)(ob + chunk * 8) = v;
  }
}

// ---------------- host ----------------
extern "C" void kernel_launch(void* const* d_in, const int* in_sizes, int n_in,
                              void* d_out, int out_size, void* d_ws, size_t ws_size,
                              hipStream_t stream) {
  const float* hs    = (const float*)d_in[0];
  const float* cosb  = (const float*)d_in[1];
  const float* sinb  = (const float*)d_in[2];
  const float* Wq    = (const float*)d_in[4];
  const float* Wk    = (const float*)d_in[5];
  const float* Wv    = (const float*)d_in[6];
  const float* Wo    = (const float*)d_in[7];
  const float* sinks = (const float*)d_in[8];
  float* out = (float*)d_out;

  static bool attr_done = false;
  if (!attr_done) {
    hipFuncSetAttribute(reinterpret_cast<const void*>(&gemm_qkv),
                        hipFuncAttributeMaxDynamicSharedMemorySize, 131072);
    attr_done = true;
  }

  char* ws = (char*)d_ws;
  short* Xb    = (short*)ws;                    // 16.78 MB  [2048][4096]
  short* Wqkvt = (short*)(ws + 16777216);       // 50.33 MB  [6144][4096]
  short* Qb    = (short*)(ws + 67108864);       // 16.78 MB  [2048][4096]
  short* Kb    = (short*)(ws + 83886080);       //  4.19 MB  [2048][1024]
  short* Vtb   = (short*)(ws + 88080384);       //  4.19 MB  [1024][2048]
  short* Ab    = Xb;                            // alias: X dead after qkv GEMM
  short* Wot   = Wqkvt;                         // alias: dead after qkv GEMM

  cvt_f32_bf16<<<8192, 256, 0, stream>>>(hs, Xb, 2097152);
  transpose_to_bf16<<<dim3(128, 128), 256, 0, stream>>>(Wq, Wqkvt, 4096, 4096);
  transpose_to_bf16<<<dim3(32, 128), 256, 0, stream>>>(Wk, Wqkvt + (size_t)4096 * 4096, 4096, 1024);
  transpose_to_bf16<<<dim3(32, 128), 256, 0, stream>>>(Wv, Wqkvt + (size_t)5120 * 4096, 4096, 1024);

  gemm_qkv<<<dim3(24, 8), 512, 131072, stream>>>(Xb, Wqkvt, Qb, Kb, Vtb, cosb, sinb);

  transpose_to_bf16<<<dim3(128, 128), 256, 0, stream>>>(Wo, Wot, 4096, 4096);

  attn_kernel<<<dim3(32, 16), 256, 0, stream>>>(Qb, Kb, Vtb, sinks, Ab);

  gemm_out<<<dim3(32, 16), 256, 0, stream>>>(Ab, Wot, out);
}